// Round 1
// baseline (382.179 us; speedup 1.0000x reference)
//
#include <hip/hip_runtime.h>
#include <cstdint>

#define NCOLS  696     // 16 + 120 + 560 subsets of size <= 3, bitmask order
#define NGROUP 174     // NCOLS / 4
#define NREC   136     // 16 singles + 120 pairs
#define RPB    4       // rows per block (one wave per row)
#define BLOCK  256

typedef float v4f __attribute__((ext_vector_type(4)));

// Record id: single a -> a ; pair (a<b) -> 16 + b*(b-1)/2 + a.
constexpr int pr(int a, int b) { return 16 + b * (b - 1) / 2 + a; }

// Per-record source operands (lo | hi<<8): rec[r] = selpair(v[hi], v[lo]).
struct alignas(8) RecSrc { uint16_t d[NREC]; };
constexpr RecSrc make_recs() {
    RecSrc t{};
    for (int a = 0; a < 16; ++a) t.d[a] = (uint16_t)(a | (a << 8));
    int p = 16;
    for (int b = 1; b < 16; ++b)
        for (int a = 0; a < b; ++a)
            t.d[p++] = (uint16_t)(a | (b << 8));
    return t;
}

// Per-column descriptor (Lrec | Rrec<<8): out = selpair(rec[Lrec], rec[Rrec]).
struct alignas(8) ColTbl { uint16_t d[NCOLS]; };
constexpr ColTbl make_cols() {
    ColTbl t{};
    int p = 0;
    for (int h = 0; h < 16; ++h) {
        t.d[p++] = (uint16_t)(h | (h << 8));
        for (int j = 0; j < h; ++j) {
            int pjh = pr(j, h);
            t.d[p++] = (uint16_t)(pjh | (pjh << 8));
            for (int i = 0; i < j; ++i)
                t.d[p++] = (uint16_t)(pr(j, h) | (pr(i, j) << 8));
        }
    }
    return t;
}

__constant__ RecSrc g_recs = make_recs();
__constant__ ColTbl g_cols = make_cols();

// Tie-exact select. cur comparison uses the sum proxy: RN(0.5l+0.5u) =
// 0.5*RN(l+u) exactly (power-of-two scaling), so ==/> are preserved
// bit-for-bit vs the NumPy fp32 reference. Beta path kept in RN form.
__device__ __forceinline__ float2 selpair(float2 L, float2 R) {
    float curL = __fadd_rn(L.x, L.y);
    float curR = __fadd_rn(R.x, R.y);
    float bL = __fadd_rn(__fmul_rn(0.2f, L.x), __fmul_rn(0.8f, L.y));
    float bR = __fadd_rn(__fmul_rn(0.2f, R.x), __fmul_rn(0.8f, R.y));
    bool choose_right = (curL == curR) ? (bL > bR) : (curL > curR);
    return choose_right ? R : L;
}

__device__ __forceinline__ float2 col_compute(const float2* __restrict__ rec,
                                              uint32_t d) {
    float2 L = rec[d & 255u];
    float2 R = rec[(d >> 8) & 255u];
    return selpair(L, R);
}

__global__ __launch_bounds__(BLOCK) void minint_kernel(
    const float* __restrict__ xl, const float* __restrict__ xu,
    float* __restrict__ out, int batch)
{
    __shared__ float2 vals[RPB][16];
    __shared__ float2 recs[RPB][NREC];
    const int t    = threadIdx.x;
    const int w    = t >> 6;   // wave id == local row
    const int lane = t & 63;
    const int row  = blockIdx.x * RPB + w;

    // ---- Hoist ALL vmcnt-counted loads to kernel entry, before any store ----
    // After this point the store phase has zero vmcnt dependencies: no
    // s_waitcnt vmcnt(N) can drag nontemporal-store acks into the loop.
    const ushort4* colsp = (const ushort4*)g_cols.d;
    const ushort4 d0 = colsp[lane];
    const ushort4 d1 = colsp[lane + 64];
    const bool has3  = lane < (NGROUP - 128);            // lanes 0..45
    const ushort4 d2 = colsp[has3 ? lane + 128 : lane];  // clamped, always valid

    const uint32_t s0 = g_recs.d[lane];
    const uint32_t s1 = g_recs.d[lane + 64];
    const bool hasR2  = lane < (NREC - 128);             // lanes 0..7
    const uint32_t s2 = g_recs.d[hasR2 ? lane + 128 : lane];

    // ---- Wave-private staging: each wave stages its OWN row. No block
    // barriers anywhere — vals[w]/recs[w] are wave-local; the DS pipe is
    // in-order per wave and the compiler orders LDS RAW via lgkmcnt.
    if (lane < 16) {
        vals[w][lane] = make_float2(xl[row * 16 + lane], xu[row * 16 + lane]);
    }
    __builtin_amdgcn_wave_barrier();   // block code motion across the staging

    const float2* v = vals[w];

    // ---- Records: 136 single/pair records, unrolled strided-by-64 ----
    {
        float2 lo = v[s0 & 15u], hi = v[(s0 >> 8) & 15u];
        recs[w][lane] = selpair(hi, lo);
        lo = v[s1 & 15u]; hi = v[(s1 >> 8) & 15u];
        recs[w][lane + 64] = selpair(hi, lo);
        if (hasR2) {
            lo = v[s2 & 15u]; hi = v[(s2 >> 8) & 15u];
            recs[w][lane + 128] = selpair(hi, lo);
        }
    }
    __builtin_amdgcn_wave_barrier();

    const float2* rec = recs[w];
    float* outl = out + (size_t)row * NCOLS;
    float* outu = out + (size_t)batch * NCOLS + (size_t)row * NCOLS;

    // ---- Column phase: per iteration only lgkmcnt-coupled ds_reads + VALU
    // + fire-and-forget nontemporal stores. Row byte stride = 696*4 = 174*16,
    // so float4 stores stay 16B-aligned.
#define DO_GROUP(gi, dd) do {                                        \
        float2 c0 = col_compute(rec, (dd).x);                        \
        float2 c1 = col_compute(rec, (dd).y);                        \
        float2 c2 = col_compute(rec, (dd).z);                        \
        float2 c3 = col_compute(rec, (dd).w);                        \
        v4f rl = { c0.x, c1.x, c2.x, c3.x };                         \
        v4f ru = { c0.y, c1.y, c2.y, c3.y };                         \
        __builtin_nontemporal_store(rl, (v4f*)(outl + 4 * (gi)));    \
        __builtin_nontemporal_store(ru, (v4f*)(outu + 4 * (gi)));    \
    } while (0)

    DO_GROUP(lane,       d0);
    DO_GROUP(lane + 64,  d1);
    if (has3) DO_GROUP(lane + 128, d2);
#undef DO_GROUP
}

extern "C" void kernel_launch(void* const* d_in, const int* in_sizes, int n_in,
                              void* d_out, int out_size, void* d_ws, size_t ws_size,
                              hipStream_t stream) {
    const float* xl = (const float*)d_in[0];
    const float* xu = (const float*)d_in[1];
    float* out = (float*)d_out;
    const int batch = in_sizes[0] / 16;          // 65536
    const int grid  = batch / RPB;               // 16384 blocks x 4 waves
    minint_kernel<<<grid, BLOCK, 0, stream>>>(xl, xu, out, batch);
}